// Round 1
// baseline (159.888 us; speedup 1.0000x reference)
//
#include <hip/hip_runtime.h>
#include <hip/hip_bf16.h>

#define NN 512
#define SDIM 16
#define MDIM 32
#define HM 64
#define NSTEPS 5

typedef __attribute__((ext_vector_type(8))) short short8;
typedef __attribute__((ext_vector_type(4))) float floatx4;

static __device__ __forceinline__ unsigned short f2bf(float f) {
    union { float f; unsigned u; } x; x.f = f;
    unsigned r = x.u + 0x7fffu + ((x.u >> 16) & 1u);
    return (unsigned short)(r >> 16);
}

// ---------------- init: transpose J, bias-only a0/c0 (h0=0), pack W2 to bf16 frags ----------
__global__ void init_kernel(const float* __restrict__ J, const float* __restrict__ b,
                            const float* __restrict__ W1, const float* __restrict__ b1,
                            const float* __restrict__ W2,
                            float* __restrict__ Jt, float* __restrict__ aG, float* __restrict__ cG,
                            float* __restrict__ h0, float* __restrict__ wJ,
                            unsigned short* __restrict__ W2bf)
{
    int bx = blockIdx.x, tid = threadIdx.x;
    if (bx < 64) {
        __shared__ float tile[64][65];
        int ti = bx >> 3, tj = bx & 7;
        for (int p = 0; p < 16; ++p) {
            int e = p*256 + tid; int r = e >> 6, c = e & 63;
            tile[r][c] = J[(ti*64 + r)*512 + tj*64 + c];
        }
        __syncthreads();
        for (int p = 0; p < 16; ++p) {
            int e = p*256 + tid; int r = e >> 6, c = e & 63;
            Jt[(tj*64 + r)*512 + ti*64 + c] = tile[c][r];   // Jt[j][i] = J[i][j]
        }
    } else if (bx < 96) {
        int gid = (bx - 64)*256 + tid;
        for (int p = 0; p < 4; ++p) {
            int idx = p*8192 + gid;
            int i = idx >> 6, o = idx & 63;
            aG[idx] = b[i] * W1[o*35 + 33];                 // h0=0 -> only b_i*w_bi
        }
    } else if (bx < 128) {
        int gid = (bx - 96)*256 + tid;
        for (int p = 0; p < 4; ++p) {
            int idx = p*8192 + gid;
            int i = idx >> 6, o = idx & 63;
            cG[idx] = b[i] * W1[o*35 + 34] + b1[o];         // b_j*w_bj + b1
        }
    } else if (bx == 128) {
        // B-frag pack: flat = ((nt*2+ks)*64 + lane)*8 + jj ; B[k][n] = W2[n][k]
        for (int p = 0; p < 16; ++p) {
            int flat = p*256 + tid;
            int jj = flat & 7;
            int lane = (flat >> 3) & 63;
            int tk = flat >> 9;            // nt*2+ks
            int nt = tk >> 1, ks = tk & 1;
            int n = nt*16 + (lane & 15);
            int k = ks*32 + (lane >> 4)*8 + jj;
            W2bf[flat] = f2bf(W2[n*64 + k]);
        }
        if (tid < 64) wJ[tid] = W1[tid*35 + 32];
    } else {
        for (int p = 0; p < 32; ++p) h0[p*256 + tid] = 0.f;
    }
}

// ---------------- edge step: per-j block, MFMA over all i, fused GRU + next projections -----
__global__ __launch_bounds__(256) void edge_kernel(
    const float* __restrict__ Jt,
    const float* __restrict__ aIn, const float* __restrict__ cIn, const float* __restrict__ hIn,
    float* __restrict__ aOut, float* __restrict__ cOut, float* __restrict__ hOut,
    const unsigned short* __restrict__ W2bf, const float* __restrict__ wJ,
    const float* __restrict__ b2, const float* __restrict__ W3, const float* __restrict__ b3,
    const float* __restrict__ W_ih, const float* __restrict__ b_ih,
    const float* __restrict__ W_hh, const float* __restrict__ b_hh,
    const float* __restrict__ W1, const float* __restrict__ bvec, const float* __restrict__ b1)
{
    const int j = blockIdx.x;
    const int tid = threadIdx.x;
    const int l = tid & 63, w = tid >> 6;
    const int m = l & 15, q = l >> 4;

    __shared__ float smWave[4][64];
    __shared__ float smMacc[64];
    __shared__ float smMsg[32];
    __shared__ float smGi[48], smGh[48];
    __shared__ float smH[16];

    // per-lane k-set: {q*8..q*8+7} and {32+q*8..32+q*8+7}
    const floatx4* c4 = (const floatx4*)cIn;
    const floatx4* w4 = (const floatx4*)wJ;
    floatx4 cva = c4[j*16 + q*2],     cvb = c4[j*16 + q*2 + 1];
    floatx4 cvc = c4[j*16 + 8 + q*2], cvd = c4[j*16 + 8 + q*2 + 1];
    floatx4 wva = w4[q*2], wvb = w4[q*2+1], wvc = w4[8+q*2], wvd = w4[8+q*2+1];

    short8 bf[4][2];
    {
        const short8* wb = (const short8*)W2bf;
        #pragma unroll
        for (int nt = 0; nt < 4; ++nt)
            #pragma unroll
            for (int ks = 0; ks < 2; ++ks)
                bf[nt][ks] = wb[(nt*2 + ks)*64 + l];
    }
    float b2n[4];
    #pragma unroll
    for (int nt = 0; nt < 4; ++nt) b2n[nt] = b2[nt*16 + m];

    floatx4 acc[4];
    #pragma unroll
    for (int nt = 0; nt < 4; ++nt) acc[nt] = (floatx4){0.f,0.f,0.f,0.f};

    const floatx4* a4 = (const floatx4*)aIn;

    for (int c8 = 0; c8 < 8; ++c8) {
        int i = w*128 + c8*16 + m;
        float Jij = Jt[j*512 + i];
        floatx4 av0 = a4[i*16 + q*2],     av1 = a4[i*16 + q*2 + 1];
        floatx4 av2 = a4[i*16 + 8 + q*2], av3 = a4[i*16 + 8 + q*2 + 1];
        floatx4 x0, x1, x2, x3;
        #pragma unroll
        for (int e = 0; e < 4; ++e) {
            x0[e] = fmaxf(fmaf(Jij, wva[e], av0[e]) + cva[e], 0.f);
            x1[e] = fmaxf(fmaf(Jij, wvb[e], av1[e]) + cvb[e], 0.f);
            x2[e] = fmaxf(fmaf(Jij, wvc[e], av2[e]) + cvc[e], 0.f);
            x3[e] = fmaxf(fmaf(Jij, wvd[e], av3[e]) + cvd[e], 0.f);
        }
        short8 fa0, fa1;
        #pragma unroll
        for (int e = 0; e < 4; ++e) {
            fa0[e]   = (short)f2bf(x0[e]);
            fa0[e+4] = (short)f2bf(x1[e]);
            fa1[e]   = (short)f2bf(x2[e]);
            fa1[e+4] = (short)f2bf(x3[e]);
        }
        #pragma unroll
        for (int nt = 0; nt < 4; ++nt) {
            floatx4 d = {0.f,0.f,0.f,0.f};
            d = __builtin_amdgcn_mfma_f32_16x16x32_bf16(fa0, bf[nt][0], d, 0, 0, 0);
            d = __builtin_amdgcn_mfma_f32_16x16x32_bf16(fa1, bf[nt][1], d, 0, 0, 0);
            #pragma unroll
            for (int r = 0; r < 4; ++r)
                acc[nt][r] += fmaxf(d[r] + b2n[nt], 0.f);
        }
    }

    // reduce rows: 4 regs (rows q*4+r) then butterfly across quads
    #pragma unroll
    for (int nt = 0; nt < 4; ++nt) {
        float v = acc[nt][0] + acc[nt][1] + acc[nt][2] + acc[nt][3];
        v += __shfl_xor(v, 16);
        v += __shfl_xor(v, 32);
        if (l < 16) smWave[w][nt*16 + l] = v;
    }
    __syncthreads();
    if (tid < 64) smMacc[tid] = smWave[0][tid] + smWave[1][tid] + smWave[2][tid] + smWave[3][tid];
    __syncthreads();
    if (tid < 32) {  // m_j = W3 @ macc + 512*b3
        float s = 512.f * b3[tid];
        for (int k = 0; k < 64; ++k) s += W3[tid*64 + k] * smMacc[k];
        smMsg[tid] = s;
    }
    __syncthreads();
    if (tid < 48) {  // GRU gates
        float gi = b_ih[tid];
        for (int c = 0; c < 16; ++c) gi += W_ih[tid*48 + c] * hIn[j*16 + c];
        for (int c = 0; c < 32; ++c) gi += W_ih[tid*48 + 16 + c] * smMsg[c];
        float gh = b_hh[tid];
        for (int s = 0; s < 16; ++s) gh += W_hh[tid*16 + s] * hIn[j*16 + s];
        smGi[tid] = gi; smGh[tid] = gh;
    }
    __syncthreads();
    if (tid < 16) {
        float r = 1.f / (1.f + __expf(-(smGi[tid] + smGh[tid])));
        float z = 1.f / (1.f + __expf(-(smGi[16+tid] + smGh[16+tid])));
        float n = tanhf(smGi[32+tid] + r * smGh[32+tid]);
        float hn = (1.f - z)*n + z*hIn[j*16 + tid];
        hOut[j*16 + tid] = hn;
        smH[tid] = hn;
    }
    __syncthreads();
    if (tid < 64) {  // next-step projections for node j
        int o = tid;
        float da = 0.f, dc = 0.f;
        for (int s = 0; s < 16; ++s) {
            da += W1[o*35 + s]      * smH[s];
            dc += W1[o*35 + 16 + s] * smH[s];
        }
        aOut[j*64 + o] = da + bvec[j]*W1[o*35+33];
        cOut[j*64 + o] = dc + bvec[j]*W1[o*35+34] + b1[o];
    }
}

// ---------------- readout ----------------
__global__ void readout_kernel(const float* __restrict__ h,
    const float* __restrict__ Wr1, const float* __restrict__ br1,
    const float* __restrict__ Wr2, const float* __restrict__ br2,
    const float* __restrict__ Wr3, const float* __restrict__ br3,
    float* __restrict__ out)
{
    int tid = threadIdx.x; int l = tid & 63, w = tid >> 6;
    int node = blockIdx.x*4 + w;
    __shared__ float sm[4][64];
    float y1 = br1[l];
    for (int s = 0; s < 16; ++s) y1 += Wr1[l*16 + s] * h[node*16 + s];
    y1 = fmaxf(y1, 0.f);
    sm[w][l] = y1;
    __syncthreads();
    float y2 = br2[l];
    for (int k = 0; k < 64; ++k) y2 += Wr2[l*64 + k] * sm[w][k];
    y2 = fmaxf(y2, 0.f);
    __syncthreads();
    sm[w][l] = y2;
    __syncthreads();
    if (l == 0) {
        float s0 = br3[0], s1 = br3[1];
        for (int k = 0; k < 64; ++k) { s0 += Wr3[k]*sm[w][k]; s1 += Wr3[64+k]*sm[w][k]; }
        float e0 = 1.f/(1.f + __expf(-s0));
        float e1 = 1.f/(1.f + __expf(-s1));
        float t = e0 + e1;
        out[node*2]     = e0/t;
        out[node*2 + 1] = e1/t;
    }
}

extern "C" void kernel_launch(void* const* d_in, const int* in_sizes, int n_in,
                              void* d_out, int out_size, void* d_ws, size_t ws_size,
                              hipStream_t stream)
{
    const float* J    = (const float*)d_in[0];
    const float* b    = (const float*)d_in[1];
    const float* W1   = (const float*)d_in[2];
    const float* b1   = (const float*)d_in[3];
    const float* W2   = (const float*)d_in[4];
    const float* b2   = (const float*)d_in[5];
    const float* W3   = (const float*)d_in[6];
    const float* b3   = (const float*)d_in[7];
    const float* W_ih = (const float*)d_in[8];
    const float* b_ih = (const float*)d_in[9];
    const float* W_hh = (const float*)d_in[10];
    const float* b_hh = (const float*)d_in[11];
    const float* Wr1  = (const float*)d_in[12];
    const float* br1  = (const float*)d_in[13];
    const float* Wr2  = (const float*)d_in[14];
    const float* br2  = (const float*)d_in[15];
    const float* Wr3  = (const float*)d_in[16];
    const float* br3  = (const float*)d_in[17];
    float* out = (float*)d_out;

    float* ws  = (float*)d_ws;
    float* Jt  = ws;
    float* aG0 = ws + 262144;
    float* aG1 = aG0 + 32768;
    float* cG0 = aG1 + 32768;
    float* cG1 = cG0 + 32768;
    float* hA  = cG1 + 32768;
    float* hB  = hA + 8192;
    float* wJ  = hB + 8192;
    unsigned short* W2bf = (unsigned short*)(wJ + 64);

    hipLaunchKernelGGL(init_kernel, dim3(130), dim3(256), 0, stream,
                       J, b, W1, b1, W2, Jt, aG0, cG0, hA, wJ, W2bf);

    float* aIn = aG0; float* aOut = aG1;
    float* cIn = cG0; float* cOut = cG1;
    float* hI  = hA;  float* hO  = hB;
    for (int t = 0; t < NSTEPS; ++t) {
        hipLaunchKernelGGL(edge_kernel, dim3(512), dim3(256), 0, stream,
            Jt, aIn, cIn, hI, aOut, cOut, hO, W2bf, wJ, b2, W3, b3,
            W_ih, b_ih, W_hh, b_hh, W1, b, b1);
        float* tmp;
        tmp = aIn; aIn = aOut; aOut = tmp;
        tmp = cIn; cIn = cOut; cOut = tmp;
        tmp = hI;  hI  = hO;  hO  = tmp;
    }
    hipLaunchKernelGGL(readout_kernel, dim3(128), dim3(256), 0, stream,
        hI, Wr1, br1, Wr2, br2, Wr3, br3, out);
}

// Round 2
// 158.989 us; speedup vs baseline: 1.0057x; 1.0057x over previous
//
#include <hip/hip_runtime.h>
#include <hip/hip_bf16.h>

#define NN 512
#define NSTEPS 5

typedef __attribute__((ext_vector_type(8))) short short8;
typedef __attribute__((ext_vector_type(4))) float floatx4;

static __device__ __forceinline__ unsigned short f2bf(float f) {
    union { float f; unsigned u; } x; x.f = f;
    unsigned r = x.u + 0x7fffu + ((x.u >> 16) & 1u);
    return (unsigned short)(r >> 16);
}

static __device__ __forceinline__ unsigned pk2bf(float a, float b) {
    __hip_bfloat162 h = __float22bfloat162_rn(make_float2(a, b));
    return *reinterpret_cast<unsigned*>(&h);
}

// ---------------- init: transpose J, bias-only a0/c0 (h0=0), pack W2 frags, split W1 --------
__global__ void init_kernel(const float* __restrict__ J, const float* __restrict__ b,
                            const float* __restrict__ W1, const float* __restrict__ b1,
                            const float* __restrict__ W2,
                            float* __restrict__ Jt, float* __restrict__ aG, float* __restrict__ cG,
                            float* __restrict__ h0, float* __restrict__ wJ,
                            float* __restrict__ wbi, float* __restrict__ wbj,
                            float* __restrict__ W1hiT, float* __restrict__ W1hjT,
                            unsigned short* __restrict__ W2bf)
{
    int bx = blockIdx.x, tid = threadIdx.x;
    if (bx < 64) {
        __shared__ float tile[64][65];
        int ti = bx >> 3, tj = bx & 7;
        for (int p = 0; p < 16; ++p) {
            int e = p*256 + tid; int r = e >> 6, c = e & 63;
            tile[r][c] = J[(ti*64 + r)*512 + tj*64 + c];
        }
        __syncthreads();
        for (int p = 0; p < 16; ++p) {
            int e = p*256 + tid; int r = e >> 6, c = e & 63;
            Jt[(tj*64 + r)*512 + ti*64 + c] = tile[c][r];   // Jt[j][i] = J[i][j]
        }
    } else if (bx < 96) {
        int gid = (bx - 64)*256 + tid;
        for (int p = 0; p < 4; ++p) {
            int idx = p*8192 + gid;
            int i = idx >> 6, o = idx & 63;
            aG[idx] = b[i] * W1[o*35 + 33];                 // h0=0 -> only b_i*w_bi
        }
    } else if (bx < 128) {
        int gid = (bx - 96)*256 + tid;
        for (int p = 0; p < 4; ++p) {
            int idx = p*8192 + gid;
            int i = idx >> 6, o = idx & 63;
            cG[idx] = b[i] * W1[o*35 + 34] + b1[o];         // b_j*w_bj + b1
        }
    } else if (bx == 128) {
        // B-frag pack: flat = ((nt*2+ks)*64 + lane)*8 + jj ; B[k][n] = W2[n][k]
        for (int p = 0; p < 16; ++p) {
            int flat = p*256 + tid;
            int jj = flat & 7;
            int lane = (flat >> 3) & 63;
            int tk = flat >> 9;            // nt*2+ks
            int nt = tk >> 1, ks = tk & 1;
            int n = nt*16 + (lane & 15);
            int k = ks*32 + (lane >> 4)*8 + jj;
            W2bf[flat] = f2bf(W2[n*64 + k]);
        }
        if (tid < 64) {
            wJ[tid]  = W1[tid*35 + 32];
            wbi[tid] = W1[tid*35 + 33];
            wbj[tid] = W1[tid*35 + 34];
            #pragma unroll
            for (int s = 0; s < 16; ++s) {
                W1hiT[tid*16 + s] = W1[tid*35 + s];
                W1hjT[tid*16 + s] = W1[tid*35 + 16 + s];
            }
        }
    } else {
        for (int p = 0; p < 32; ++p) h0[p*256 + tid] = 0.f;
    }
}

// ---------------- edge step: per-j block, MFMA over all i, fused GRU + next proj (+readout) --
__global__ __launch_bounds__(256) void edge_kernel(
    const float* __restrict__ Jt,
    const float* __restrict__ aIn, const float* __restrict__ cIn, const float* __restrict__ hIn,
    float* __restrict__ aOut, float* __restrict__ cOut, float* __restrict__ hOut,
    const unsigned short* __restrict__ W2bf, const float* __restrict__ wJ,
    const float* __restrict__ b2, const float* __restrict__ W3, const float* __restrict__ b3,
    const float* __restrict__ W_ih, const float* __restrict__ b_ih,
    const float* __restrict__ W_hh, const float* __restrict__ b_hh,
    const float* __restrict__ W1hiT, const float* __restrict__ W1hjT,
    const float* __restrict__ wbi, const float* __restrict__ wbj,
    const float* __restrict__ bvec, const float* __restrict__ b1,
    const float* __restrict__ Wr1, const float* __restrict__ br1,
    const float* __restrict__ Wr2, const float* __restrict__ br2,
    const float* __restrict__ Wr3, const float* __restrict__ br3,
    float* __restrict__ out, int last)
{
    const int j = blockIdx.x;
    const int tid = threadIdx.x;
    const int l = tid & 63, w = tid >> 6;
    const int m = l & 15, q = l >> 4;

    __shared__ float smWave[4][64];
    __shared__ float smMacc[64];
    __shared__ float smGin[48];      // [h(16), msg(32)]
    __shared__ float smGi[48], smGh[48];
    __shared__ float smH[16];
    __shared__ float smY[64];
    __shared__ float smR[2];

    // per-lane k-set: {q*8..q*8+7} and {32+q*8..32+q*8+7}
    const floatx4* c4 = (const floatx4*)cIn;
    const floatx4* w4 = (const floatx4*)wJ;
    floatx4 cva = c4[j*16 + q*2],     cvb = c4[j*16 + q*2 + 1];
    floatx4 cvc = c4[j*16 + 8 + q*2], cvd = c4[j*16 + 8 + q*2 + 1];
    floatx4 wva = w4[q*2], wvb = w4[q*2+1], wvc = w4[8+q*2], wvd = w4[8+q*2+1];

    short8 bfw[4][2];
    {
        const short8* wb = (const short8*)W2bf;
        #pragma unroll
        for (int nt = 0; nt < 4; ++nt)
            #pragma unroll
            for (int ks = 0; ks < 2; ++ks)
                bfw[nt][ks] = wb[(nt*2 + ks)*64 + l];
    }
    float b2n[4];
    #pragma unroll
    for (int nt = 0; nt < 4; ++nt) b2n[nt] = b2[nt*16 + m];

    floatx4 acc[4];
    #pragma unroll
    for (int nt = 0; nt < 4; ++nt) acc[nt] = (floatx4){0.f,0.f,0.f,0.f};

    const floatx4* a4 = (const floatx4*)aIn;

    for (int c8 = 0; c8 < 8; ++c8) {
        int i = w*128 + c8*16 + m;
        float Jij = Jt[j*512 + i];
        floatx4 av0 = a4[i*16 + q*2],     av1 = a4[i*16 + q*2 + 1];
        floatx4 av2 = a4[i*16 + 8 + q*2], av3 = a4[i*16 + 8 + q*2 + 1];
        floatx4 x0, x1, x2, x3;
        #pragma unroll
        for (int e = 0; e < 4; ++e) {
            x0[e] = fmaxf(fmaf(Jij, wva[e], av0[e]) + cva[e], 0.f);
            x1[e] = fmaxf(fmaf(Jij, wvb[e], av1[e]) + cvb[e], 0.f);
            x2[e] = fmaxf(fmaf(Jij, wvc[e], av2[e]) + cvc[e], 0.f);
            x3[e] = fmaxf(fmaf(Jij, wvd[e], av3[e]) + cvd[e], 0.f);
        }
        union { short8 s; unsigned u[4]; } fa0, fa1;
        fa0.u[0] = pk2bf(x0[0], x0[1]); fa0.u[1] = pk2bf(x0[2], x0[3]);
        fa0.u[2] = pk2bf(x1[0], x1[1]); fa0.u[3] = pk2bf(x1[2], x1[3]);
        fa1.u[0] = pk2bf(x2[0], x2[1]); fa1.u[1] = pk2bf(x2[2], x2[3]);
        fa1.u[2] = pk2bf(x3[0], x3[1]); fa1.u[3] = pk2bf(x3[2], x3[3]);
        #pragma unroll
        for (int nt = 0; nt < 4; ++nt) {
            floatx4 d = {0.f,0.f,0.f,0.f};
            d = __builtin_amdgcn_mfma_f32_16x16x32_bf16(fa0.s, bfw[nt][0], d, 0, 0, 0);
            d = __builtin_amdgcn_mfma_f32_16x16x32_bf16(fa1.s, bfw[nt][1], d, 0, 0, 0);
            #pragma unroll
            for (int r = 0; r < 4; ++r)
                acc[nt][r] += fmaxf(d[r] + b2n[nt], 0.f);
        }
    }

    // reduce rows within wave, stage h into smGin
    #pragma unroll
    for (int nt = 0; nt < 4; ++nt) {
        float v = acc[nt][0] + acc[nt][1] + acc[nt][2] + acc[nt][3];
        v += __shfl_xor(v, 16);
        v += __shfl_xor(v, 32);
        if (l < 16) smWave[w][nt*16 + l] = v;
    }
    if (tid < 16) smGin[tid] = hIn[j*16 + tid];
    __syncthreads();
    if (tid < 64) smMacc[tid] = smWave[0][tid] + smWave[1][tid] + smWave[2][tid] + smWave[3][tid];
    __syncthreads();

    // msg = W3 @ macc + 512*b3  — 256 threads: out=tid>>3 (32), p=tid&7 (8 k-chunks)
    {
        int o = tid >> 3, p = tid & 7;
        const floatx4* W3v = (const floatx4*)W3;
        floatx4 wv0 = W3v[o*16 + p*2], wv1 = W3v[o*16 + p*2 + 1];
        float part = 0.f;
        #pragma unroll
        for (int e = 0; e < 4; ++e) {
            part = fmaf(wv0[e], smMacc[p*8 + e], part);
            part = fmaf(wv1[e], smMacc[p*8 + 4 + e], part);
        }
        part += __shfl_xor(part, 1);
        part += __shfl_xor(part, 2);
        part += __shfl_xor(part, 4);
        if (p == 0) smGin[16 + o] = part + 512.f * b3[o];
    }
    __syncthreads();

    // GRU gates: gi on threads 0..191 (4 per output), gh on 192..239
    if (tid < 192) {
        int o = tid >> 2, p = tid & 3;
        const floatx4* Wv = (const floatx4*)W_ih;
        floatx4 w0 = Wv[o*12 + p*3], w1 = Wv[o*12 + p*3 + 1], w2 = Wv[o*12 + p*3 + 2];
        int k0 = p*12;
        float part = 0.f;
        #pragma unroll
        for (int e = 0; e < 4; ++e) {
            part = fmaf(w0[e], smGin[k0 + e], part);
            part = fmaf(w1[e], smGin[k0 + 4 + e], part);
            part = fmaf(w2[e], smGin[k0 + 8 + e], part);
        }
        part += __shfl_xor(part, 1);
        part += __shfl_xor(part, 2);
        if (p == 0) smGi[o] = part + b_ih[o];
    } else if (tid < 240) {
        int o = tid - 192;
        const floatx4* Wv = (const floatx4*)W_hh;
        floatx4 w0 = Wv[o*4], w1 = Wv[o*4+1], w2 = Wv[o*4+2], w3 = Wv[o*4+3];
        float s = b_hh[o];
        #pragma unroll
        for (int e = 0; e < 4; ++e) {
            s = fmaf(w0[e], smGin[e],      s);
            s = fmaf(w1[e], smGin[4 + e],  s);
            s = fmaf(w2[e], smGin[8 + e],  s);
            s = fmaf(w3[e], smGin[12 + e], s);
        }
        smGh[o] = s;
    }
    __syncthreads();

    if (tid < 16) {
        float r = 1.f / (1.f + __expf(-(smGi[tid] + smGh[tid])));
        float z = 1.f / (1.f + __expf(-(smGi[16+tid] + smGh[16+tid])));
        float n = tanhf(smGi[32+tid] + r * smGh[32+tid]);
        float hn = (1.f - z)*n + z*smGin[tid];
        hOut[j*16 + tid] = hn;
        smH[tid] = hn;
    }
    __syncthreads();

    if (!last) {
        // next-step projections: threads 0..63 -> a, 64..127 -> c
        if (tid < 128) {
            int o = tid & 63, sel = tid >> 6;
            const floatx4* Wv = (const floatx4*)(sel ? W1hjT : W1hiT);
            floatx4 w0 = Wv[o*4], w1 = Wv[o*4+1], w2 = Wv[o*4+2], w3 = Wv[o*4+3];
            float s = 0.f;
            #pragma unroll
            for (int e = 0; e < 4; ++e) {
                s = fmaf(w0[e], smH[e],      s);
                s = fmaf(w1[e], smH[4 + e],  s);
                s = fmaf(w2[e], smH[8 + e],  s);
                s = fmaf(w3[e], smH[12 + e], s);
            }
            if (sel == 0) aOut[j*64 + o] = s + bvec[j]*wbi[o];
            else          cOut[j*64 + o] = s + bvec[j]*wbj[o] + b1[o];
        }
    } else {
        // fused readout for node j
        if (tid < 64) {
            const floatx4* Wv = (const floatx4*)Wr1;
            floatx4 w0 = Wv[tid*4], w1 = Wv[tid*4+1], w2 = Wv[tid*4+2], w3 = Wv[tid*4+3];
            float s = br1[tid];
            #pragma unroll
            for (int e = 0; e < 4; ++e) {
                s = fmaf(w0[e], smH[e],      s);
                s = fmaf(w1[e], smH[4 + e],  s);
                s = fmaf(w2[e], smH[8 + e],  s);
                s = fmaf(w3[e], smH[12 + e], s);
            }
            smY[tid] = fmaxf(s, 0.f);
        }
        __syncthreads();
        {   // y2: 64 outputs x 64 inputs, 4 threads per output
            int o = tid >> 2, p = tid & 3;
            const floatx4* Wv = (const floatx4*)Wr2;
            floatx4 w0 = Wv[o*16 + p*4],     w1 = Wv[o*16 + p*4 + 1];
            floatx4 w2 = Wv[o*16 + p*4 + 2], w3 = Wv[o*16 + p*4 + 3];
            int k0 = p*16;
            float part = 0.f;
            #pragma unroll
            for (int e = 0; e < 4; ++e) {
                part = fmaf(w0[e], smY[k0 + e],      part);
                part = fmaf(w1[e], smY[k0 + 4 + e],  part);
                part = fmaf(w2[e], smY[k0 + 8 + e],  part);
                part = fmaf(w3[e], smY[k0 + 12 + e], part);
            }
            part += __shfl_xor(part, 1);
            part += __shfl_xor(part, 2);
            __syncthreads();
            if (p == 0) smY[o] = fmaxf(part + br2[o], 0.f);
        }
        __syncthreads();
        if (tid < 128) {
            int ot = tid >> 6, p = tid & 63;
            float part = Wr3[ot*64 + p] * smY[p];
            part += __shfl_xor(part, 1);
            part += __shfl_xor(part, 2);
            part += __shfl_xor(part, 4);
            part += __shfl_xor(part, 8);
            part += __shfl_xor(part, 16);
            part += __shfl_xor(part, 32);
            if (p == 0) smR[ot] = part + br3[ot];
        }
        __syncthreads();
        if (tid == 0) {
            float e0 = 1.f/(1.f + __expf(-smR[0]));
            float e1 = 1.f/(1.f + __expf(-smR[1]));
            float t = e0 + e1;
            out[j*2]     = e0/t;
            out[j*2 + 1] = e1/t;
        }
    }
}

extern "C" void kernel_launch(void* const* d_in, const int* in_sizes, int n_in,
                              void* d_out, int out_size, void* d_ws, size_t ws_size,
                              hipStream_t stream)
{
    const float* J    = (const float*)d_in[0];
    const float* b    = (const float*)d_in[1];
    const float* W1   = (const float*)d_in[2];
    const float* b1   = (const float*)d_in[3];
    const float* W2   = (const float*)d_in[4];
    const float* b2   = (const float*)d_in[5];
    const float* W3   = (const float*)d_in[6];
    const float* b3   = (const float*)d_in[7];
    const float* W_ih = (const float*)d_in[8];
    const float* b_ih = (const float*)d_in[9];
    const float* W_hh = (const float*)d_in[10];
    const float* b_hh = (const float*)d_in[11];
    const float* Wr1  = (const float*)d_in[12];
    const float* br1  = (const float*)d_in[13];
    const float* Wr2  = (const float*)d_in[14];
    const float* br2  = (const float*)d_in[15];
    const float* Wr3  = (const float*)d_in[16];
    const float* br3  = (const float*)d_in[17];
    float* out = (float*)d_out;

    float* ws   = (float*)d_ws;
    float* Jt   = ws;
    float* aG0  = Jt + 262144;
    float* aG1  = aG0 + 32768;
    float* cG0  = aG1 + 32768;
    float* cG1  = cG0 + 32768;
    float* hA   = cG1 + 32768;
    float* hB   = hA + 8192;
    float* wJ   = hB + 8192;
    float* wbi  = wJ + 64;
    float* wbj  = wbi + 64;
    float* W1hiT = wbj + 64;
    float* W1hjT = W1hiT + 1024;
    unsigned short* W2bf = (unsigned short*)(W1hjT + 1024);

    hipLaunchKernelGGL(init_kernel, dim3(130), dim3(256), 0, stream,
                       J, b, W1, b1, W2, Jt, aG0, cG0, hA, wJ, wbi, wbj, W1hiT, W1hjT, W2bf);

    float* aIn = aG0; float* aOut = aG1;
    float* cIn = cG0; float* cOut = cG1;
    float* hI  = hA;  float* hO  = hB;
    for (int t = 0; t < NSTEPS; ++t) {
        hipLaunchKernelGGL(edge_kernel, dim3(512), dim3(256), 0, stream,
            Jt, aIn, cIn, hI, aOut, cOut, hO, W2bf, wJ, b2, W3, b3,
            W_ih, b_ih, W_hh, b_hh, W1hiT, W1hjT, wbi, wbj, b, b1,
            Wr1, br1, Wr2, br2, Wr3, br3, out, (t == NSTEPS-1) ? 1 : 0);
        float* tmp;
        tmp = aIn; aIn = aOut; aOut = tmp;
        tmp = cIn; cIn = cOut; cOut = tmp;
        tmp = hI;  hI  = hO;  hO  = tmp;
    }
}